// Round 4
// baseline (244.598 us; speedup 1.0000x reference)
//
#include <hip/hip_runtime.h>

#define CH    512
#define BATCH 16
#define HW    3136     // 56*56
#define HW4   784      // HW/4 (float4 per image plane)
#define THRESH 8.0f
#define NBLK  (CH * BATCH)   // 8192 absmax blocks

typedef float f4 __attribute__((ext_vector_type(4)));

// ---- Kernel 1: per-(channel,batch) plane max|x|, last block builds plan --
__global__ __launch_bounds__(256) void absmax_plan_kernel(
        const float*   __restrict__ x,
        float*         __restrict__ partial,
        unsigned int*  __restrict__ counter,
        int*           __restrict__ rep,
        float*         __restrict__ invT,
        float*         __restrict__ out_tail) {
    const int c   = blockIdx.x;       // channel
    const int b   = blockIdx.y;       // batch
    const int tid = threadIdx.x;
    const f4* src = reinterpret_cast<const f4*>(x) + (size_t)(b * CH + c) * HW4;
    float m = 0.0f;
    for (int p = tid; p < HW4; p += 256) {
        f4 v = src[p];
        m = fmaxf(m, fmaxf(fmaxf(fabsf(v.x), fabsf(v.y)),
                           fmaxf(fabsf(v.z), fabsf(v.w))));
    }
    __shared__ float sm[256];
    sm[tid] = m;
    __syncthreads();
    for (int off = 128; off > 0; off >>= 1) {
        if (tid < off) sm[tid] = fmaxf(sm[tid], sm[tid + off]);
        __syncthreads();
    }

    __shared__ int isLast;
    if (tid == 0) {
        partial[c * BATCH + b] = sm[0];
        __threadfence();                       // publish partial before ticket
        unsigned int old = atomicAdd(counter, 1u);
        isLast = (old == NBLK - 1) ? 1 : 0;
    }
    __syncthreads();
    if (!isLast) return;
    __threadfence();                           // acquire all partial[] writes

    // ---- plan phase (runs once, in the last block): 2 channels/thread ----
    const int c0 = tid * 2, c1 = c0 + 1;
    float m0 = 0.0f, m1 = 0.0f;
    #pragma unroll
    for (int k = 0; k < BATCH; ++k) {
        m0 = fmaxf(m0, partial[c0 * BATCH + k]);
        m1 = fmaxf(m1, partial[c1 * BATCH + k]);
    }
    int T0 = (m0 > THRESH) ? (int)ceilf(m0 * 0.125f) : 0;   // /8 exact in fp32
    int T1 = (m1 > THRESH) ? (int)ceilf(m1 * 0.125f) : 0;
    int o0 = (T0 > 0), o1 = (T1 > 0);

    __shared__ int sT[256], sO[256];
    sT[tid] = T0 + T1;
    sO[tid] = o0 + o1;
    __syncthreads();
    for (int off = 1; off < 256; off <<= 1) {  // Hillis-Steele inclusive scan
        int a = 0, bb = 0;
        if (tid >= off) { a = sT[tid - off]; bb = sO[tid - off]; }
        __syncthreads();
        sT[tid] += a;
        sO[tid] += bb;
        __syncthreads();
    }
    const int exT = sT[tid] - (T0 + T1);       // exclusive prefix: rep slot
    const int exO = sO[tid] - (o0 + o1);       // exclusive prefix: ordinal
    if (T0 > 0) {
        out_tail[exO] = (float)c0;             // outlier channel id as fp32
        float iv = (float)(1.0 / (double)T0);  // match numpy f64->f32 rounding
        for (int k = 0; k < T0; ++k) { rep[exT + k] = c0; invT[exT + k] = iv; }
    }
    if (T1 > 0) {
        out_tail[exO + o0] = (float)c1;
        float iv = (float)(1.0 / (double)T1);
        for (int k = 0; k < T1; ++k) { rep[exT + T0 + k] = c1; invT[exT + T0 + k] = iv; }
    }
}

// ---- Kernel 2: gather + scale, NT stores, XCD-chunked swizzle (as R2) ---
__global__ __launch_bounds__(256) void gather_kernel(const float* __restrict__ x,
                                                     const int*   __restrict__ rep,
                                                     const float* __restrict__ invT,
                                                     float* __restrict__ out,
                                                     int R) {
    const int nwg  = gridDim.x;
    const int orig = blockIdx.x;
    const int xcd  = orig & 7;
    const int q = nwg >> 3, r = nwg & 7;
    const int wg = (xcd < r ? xcd * (q + 1) : r * (q + 1) + (xcd - r) * q)
                   + (orig >> 3);
    const int j = wg >> 4;        // output channel (BATCH = 16)
    const int b = wg & 15;        // batch

    const int   c = rep[j];       // wave-uniform
    const float s = invT[j];
    const f4* src = reinterpret_cast<const f4*>(x) + (size_t)(b * CH + c) * HW4;
    f4* dst = reinterpret_cast<f4*>(out) + ((size_t)b * R + j) * HW4;
    for (int p = threadIdx.x; p < HW4; p += 256) {
        f4 v = src[p];
        v.x *= s; v.y *= s; v.z *= s; v.w *= s;
        __builtin_nontemporal_store(v, &dst[p]);  // never re-read: keep x in L3
    }
}

extern "C" void kernel_launch(void* const* d_in, const int* in_sizes, int n_in,
                              void* d_out, int out_size, void* d_ws, size_t ws_size,
                              hipStream_t stream) {
    const float* x = (const float*)d_in[0];
    float* out = (float*)d_out;

    // out_size = 50176*R + n_out,  n_out <= 512 < 50176  -> unique split
    const int plane = BATCH * HW;               // 50176
    const int R     = out_size / plane;         // total replicated channels

    // workspace: [8192 floats partial][counter][rep R ints][invT R floats]
    float*        partial = (float*)d_ws;
    unsigned int* counter = (unsigned int*)((char*)d_ws + (size_t)NBLK * 4);
    int*          rep     = (int*)  ((char*)d_ws + (size_t)NBLK * 4 + 256);
    float*        invT    = (float*)((char*)d_ws + (size_t)NBLK * 4 + 256 + (size_t)R * 4);

    hipMemsetAsync(counter, 0, sizeof(unsigned int), stream);
    absmax_plan_kernel<<<dim3(CH, BATCH), 256, 0, stream>>>(
        x, partial, counter, rep, invT, out + (size_t)R * plane);
    if (R > 0) {
        gather_kernel<<<dim3(R * BATCH), 256, 0, stream>>>(x, rep, invT, out, R);
    }
}

// Round 5
// 66.615 us; speedup vs baseline: 3.6718x; 3.6718x over previous
//
#include <hip/hip_runtime.h>

#define CH    512
#define BATCH 16
#define QB    4        // batch planes per absmax block
#define NQ    (BATCH / QB)
#define HW    3136     // 56*56
#define HW4   784      // HW/4 (float4 per image plane)
#define THRESH 8.0f

typedef float f4 __attribute__((ext_vector_type(4)));

// ---- Kernel 1: partial[c*NQ+q] = max|x[b in q*QB..q*QB+3, c, :, :]| -----
__global__ __launch_bounds__(256) void absmax_kernel(const float* __restrict__ x,
                                                     float* __restrict__ partial) {
    const int c   = blockIdx.x;
    const int q   = blockIdx.y;
    const int tid = threadIdx.x;
    float m = 0.0f;
    for (int bb = 0; bb < QB; ++bb) {
        const int b = q * QB + bb;
        const f4* src = reinterpret_cast<const f4*>(x) + (size_t)(b * CH + c) * HW4;
        for (int p = tid; p < HW4; p += 256) {
            f4 v = src[p];
            m = fmaxf(m, fmaxf(fmaxf(fabsf(v.x), fabsf(v.y)),
                               fmaxf(fabsf(v.z), fabsf(v.w))));
        }
    }
    __shared__ float sm[256];
    sm[tid] = m;
    __syncthreads();
    for (int off = 128; off > 0; off >>= 1) {
        if (tid < off) sm[tid] = fmaxf(sm[tid], sm[tid + off]);
        __syncthreads();
    }
    if (tid == 0) partial[c * NQ + q] = sm[0];
}

// ---- Kernel 2: gather + scale; each block recomputes the plan locally ---
__global__ __launch_bounds__(256) void gather_kernel(const float* __restrict__ x,
                                                     const float* __restrict__ partial,
                                                     float* __restrict__ out,
                                                     float* __restrict__ out_tail,
                                                     int R) {
    // bijective XCD chunk mapping (8 XCDs): neighbor output channels stay on
    // the same XCD so replica re-reads hit that XCD's L2.
    const int nwg  = gridDim.x;
    const int orig = blockIdx.x;
    const int xcd  = orig & 7;
    const int q8 = nwg >> 3, r8 = nwg & 7;
    const int wg = (xcd < r8 ? xcd * (q8 + 1) : r8 * (q8 + 1) + (xcd - r8) * q8)
                   + (orig >> 3);
    const int j = wg >> 4;        // output channel slot (BATCH = 16)
    const int b = wg & 15;        // batch

    const int tid  = threadIdx.x;
    const int lane = tid & 63;
    const int w    = tid >> 6;    // wave id (4 waves)

    // --- local plan: thread t owns channels c0=2t, c1=2t+1 ---------------
    const int c0 = tid * 2, c1 = c0 + 1;
    f4 p0 = reinterpret_cast<const f4*>(partial)[tid * 2];      // c0's 4 partials
    f4 p1 = reinterpret_cast<const f4*>(partial)[tid * 2 + 1];  // c1's 4 partials
    float m0 = fmaxf(fmaxf(p0.x, p0.y), fmaxf(p0.z, p0.w));
    float m1 = fmaxf(fmaxf(p1.x, p1.y), fmaxf(p1.z, p1.w));
    int T0 = (m0 > THRESH) ? (int)ceilf(m0 * 0.125f) : 0;  // ceil(m/8), exact
    int T1 = (m1 > THRESH) ? (int)ceilf(m1 * 0.125f) : 0;
    const int v = T0 + T1;

    // wave-inclusive scan of v over 64 lanes (no barriers)
    int s = v;
    #pragma unroll
    for (int off = 1; off < 64; off <<= 1) {
        int t2 = __shfl_up(s, off, 64);
        if (lane >= off) s += t2;
    }
    __shared__ int wsum[4];
    if (lane == 63) wsum[w] = s;
    __syncthreads();
    int woff = 0;
    #pragma unroll
    for (int k = 0; k < 4; ++k) if (k < w) woff += wsum[k];
    const int excl   = woff + s - v;       // first output slot of channel c0
    const int start0 = excl, start1 = excl + T0;

    __shared__ int sc, sT;
    if (T0 > 0 && j >= start0 && j < start0 + T0) { sc = c0; sT = T0; }
    if (T1 > 0 && j >= start1 && j < start1 + T1) { sc = c1; sT = T1; }

    // block wg==0 additionally writes the outlier-id tail (fp32 channel ids)
    if (wg == 0) {
        const int o0 = (T0 > 0), o1 = (T1 > 0);
        const int v2 = o0 + o1;
        int s2 = v2;
        #pragma unroll
        for (int off = 1; off < 64; off <<= 1) {
            int t2 = __shfl_up(s2, off, 64);
            if (lane >= off) s2 += t2;
        }
        __shared__ int wsum2[4];
        if (lane == 63) wsum2[w] = s2;
        __syncthreads();
        int woff2 = 0;
        #pragma unroll
        for (int k = 0; k < 4; ++k) if (k < w) woff2 += wsum2[k];
        const int ex2 = woff2 + s2 - v2;
        if (o0) out_tail[ex2]      = (float)c0;
        if (o1) out_tail[ex2 + o0] = (float)c1;
    }
    __syncthreads();

    const int   c     = sc;                          // wave-uniform
    const float scale = (float)(1.0 / (double)sT);   // numpy f64->f32 rounding

    const f4* src = reinterpret_cast<const f4*>(x) + (size_t)(b * CH + c) * HW4;
    f4* dst = reinterpret_cast<f4*>(out) + ((size_t)b * R + j) * HW4;
    for (int p = tid; p < HW4; p += 256) {
        f4 vv = src[p];
        vv.x *= scale; vv.y *= scale; vv.z *= scale; vv.w *= scale;
        __builtin_nontemporal_store(vv, &dst[p]);  // never re-read: keep x in L3
    }
}

extern "C" void kernel_launch(void* const* d_in, const int* in_sizes, int n_in,
                              void* d_out, int out_size, void* d_ws, size_t ws_size,
                              hipStream_t stream) {
    const float* x = (const float*)d_in[0];
    float* out = (float*)d_out;

    // out_size = 50176*R + n_out,  n_out <= 512 < 50176  -> unique split
    const int plane = BATCH * HW;               // 50176
    const int R     = out_size / plane;         // total replicated channels

    float* partial = (float*)d_ws;              // CH*NQ floats (8 KB)

    absmax_kernel<<<dim3(CH, NQ), 256, 0, stream>>>(x, partial);
    if (R > 0) {
        gather_kernel<<<dim3(R * BATCH), 256, 0, stream>>>(
            x, partial, out, out + (size_t)R * plane, R);
    }
}